// Round 19
// baseline (67.683 us; speedup 1.0000x reference)
//
#include <hip/hip_runtime.h>
#include <math.h>

typedef __attribute__((ext_vector_type(2))) _Float16 half2v;
typedef __attribute__((ext_vector_type(2))) float f32x2;
typedef __attribute__((ext_vector_type(4), aligned(8))) unsigned int uint4a;

#define BB 4
#define HH 2048
#define WW 128
#define HP (HH + 2)   // 2050
#define WP (WW + 2)   // 130
#define PP 128        // pooled size
#define MROWS 16      // k_mat rows/block (halves fm L2 re-read vs 8)

#define BORDER_PER_B (2 * WP + 2 * (HP - 2))   // 4356

__device__ __forceinline__ half2v b2h(unsigned u) { return __builtin_bit_cast(half2v, u); }
__device__ __forceinline__ unsigned pku(float a, float b) {
    return __builtin_bit_cast(unsigned, __builtin_amdgcn_cvt_pkrtz(a, b));
}
__device__ __forceinline__ float dot2(half2v a, unsigned wb, float c) {
    return __builtin_amdgcn_fdot2(a, b2h(wb), c, false);
}
__device__ __forceinline__ float hlo(unsigned u) { return (float)b2h(u).x; }
__device__ __forceinline__ float hhi(unsigned u) { return (float)b2h(u).y; }

// XCD co-location (R12-proven; R14 granularity win). XCD k = bid%8 owns
// batch k/2, rows [(k&1)*1024, +1024) in ALL producer/consumer kernels:
//   k_mat:    512 blocks x 16 rows: swz=(bid&7)*64+(bid>>3); b=swz>>7; h0=(swz&127)*16
//   k_deform: 4096 blocks x 2 rows: swz=(bid&7)*512+(bid>>3); b=swz>>10; h=(swz&1023)*2

// ---------------------------------------------------------------------------
// Kernel 1: border-zero of xph (fused) + avg pool + 1x1 conv + sigmoid.
// (R15 frozen)
// ---------------------------------------------------------------------------
__global__ void k_fm(const float* __restrict__ rgb, const float* __restrict__ w_fm,
                     float2* __restrict__ fmp, uint2* __restrict__ xph) {
    int j = threadIdx.x;              // 0..127
    int bi = blockIdx.x;              // b*64 + t
    int tid = bi * 128 + j;

    if (tid < BB * BORDER_PER_B) {    // 17424 <= 32768 threads
        int b = tid / BORDER_PER_B;
        int r = tid - b * BORDER_PER_B;
        int row, col;
        if (r < WP)          { row = 0;      col = r; }
        else if (r < 2 * WP) { row = HP - 1; col = r - WP; }
        else {
            int q = r - 2 * WP;
            row = 1 + (q >> 1);
            col = (q & 1) ? (WP - 1) : 0;
        }
        xph[((size_t)b * HP + row) * WP + col] = make_uint2(0u, 0u);
    }

    int b = bi >> 6, t = bi & 63;     // fm rows 2t, 2t+1 <- rgb rows 32t..32t+31
    const float* r0 = rgb + ((size_t)(b * 2 + 0) * HH + (size_t)t * 32) * WW + j;
    const float* r1 = rgb + ((size_t)(b * 2 + 1) * HH + (size_t)t * 32) * WW + j;
    float sA0 = 0.f, sA1 = 0.f, sB0 = 0.f, sB1 = 0.f;
#pragma unroll
    for (int a = 0; a < 16; ++a) { sA0 += r0[a * WW]; sA1 += r1[a * WW]; }
#pragma unroll
    for (int a = 16; a < 32; ++a) { sB0 += r0[a * WW]; sB1 += r1[a * WW]; }
    sA0 *= (1.f / 16.f); sA1 *= (1.f / 16.f);
    sB0 *= (1.f / 16.f); sB1 *= (1.f / 16.f);
    float fA0 = w_fm[0] * sA0 + w_fm[1] * sA1;
    float fA1 = w_fm[2] * sA0 + w_fm[3] * sA1;
    float fB0 = w_fm[0] * sB0 + w_fm[1] * sB1;
    float fB1 = w_fm[2] * sB0 + w_fm[3] * sB1;
    float gA0 = 1.f / (1.f + expf(-fA0)), gB0 = 1.f / (1.f + expf(-fB0));
    float gA1 = 1.f / (1.f + expf(-fA1)), gB1 = 1.f / (1.f + expf(-fB1));
    fmp[((size_t)(b * 2 + 0) * 64 + t) * PP + j] = make_float2(gA0, gB0);
    fmp[((size_t)(b * 2 + 1) * 64 + t) * PP + j] = make_float2(gA1, gB1);
}

// ---------------------------------------------------------------------------
// Kernel 2: mat = rgb @ fm + rgb, fs = w_fs @ mat, xph = f16 cells.
// MROWS=16: fm panel re-read halved again (134->67MB L2).
// ---------------------------------------------------------------------------
__global__ __launch_bounds__(128) void k_mat(
        const float* __restrict__ rgb, const float* __restrict__ sar,
        const float* __restrict__ w_fs, const float2* __restrict__ fmp,
        uint2* __restrict__ xph) {
    int w = threadIdx.x;              // 0..127
    int bid = blockIdx.x;             // 0..511
    int swz = (bid & 7) * 64 + (bid >> 3);
    int b = swz >> 7;
    int h0 = (swz & 127) * 16;

    const float* rg0 = rgb + ((size_t)(b * 2 + 0) * HH + h0) * WW;  // uniform base
    const float* rg1 = rgb + ((size_t)(b * 2 + 1) * HH + h0) * WW;
    const float2* fp0 = fmp + (size_t)(b * 2 + 0) * 64 * PP;
    const float2* fp1 = fmp + (size_t)(b * 2 + 1) * 64 * PP;

    f32x2 av0[MROWS], av1[MROWS];
#pragma unroll
    for (int r = 0; r < MROWS; ++r) {                // residual term in lane .x
        av0[r] = (f32x2){rg0[r * WW + w], 0.f};
        av1[r] = (f32x2){rg1[r * WW + w], 0.f};
    }

#pragma unroll 2
    for (int t = 0; t < 64; ++t) {                   // k-pair (2t, 2t+1)
        float2 f0 = fp0[(size_t)t * PP + w];         // coalesced dwordx2
        float2 f1 = fp1[(size_t)t * PP + w];
        f32x2 fv0 = {f0.x, f0.y};
        f32x2 fv1 = {f1.x, f1.y};
#pragma unroll
        for (int r = 0; r < MROWS; ++r) {
            f32x2 a0 = *(const f32x2*)(rg0 + r * WW + 2 * t);   // uniform s_load
            f32x2 a1 = *(const f32x2*)(rg1 + r * WW + 2 * t);
            av0[r] += a0 * fv0;                      // v_pk_fma_f32
            av1[r] += a1 * fv1;
        }
    }

    float wa = w_fs[0], wb = w_fs[1], wc = w_fs[2], wd = w_fs[3];
#pragma unroll
    for (int r = 0; r < MROWS; ++r) {
        float m0 = av0[r].x + av0[r].y;
        float m1 = av1[r].x + av1[r].y;
        float fs0 = wa * m0 + wb * m1;
        float fs1 = wc * m0 + wd * m1;
        float s0 = sar[((size_t)(b * 2 + 0) * HH + (h0 + r)) * WW + w];
        float s1 = sar[((size_t)(b * 2 + 1) * HH + (h0 + r)) * WW + w];
        uint2 cell = make_uint2(pku(s0, s1), pku(fs0, fs1));
        xph[((size_t)b * HP + (h0 + r + 1)) * WP + (w + 1)] = cell;
    }
}

// ---------------------------------------------------------------------------
// Kernel 3: offset conv + deformable bilinear + deform conv, 2 px/thread,
// 128-thr blocks. n-loop at UNROLL 3 (R18 rolled-loop win + R13 load-batching
// retest now that the body is I$-resident: 3 points' 12 gathers per iter).
// Math identical to R15/R18 (absmax 0.125).
// ---------------------------------------------------------------------------
__global__ __launch_bounds__(128, 4) void k_deform(
        const float* __restrict__ w_p, const float* __restrict__ b_p,
        const float* __restrict__ w_dc, const uint2* __restrict__ xph,
        float* __restrict__ out) {
    int bid = blockIdx.x;
    int swz = (bid & 7) * 512 + (bid >> 3);
    int b = swz >> 10;
    int h = (swz & 1023) * 2;                   // this block: rows h, h+1 (uniform)
    int w = threadIdx.x;                        // 0..127

    const uint2* xb = xph + (size_t)b * HP * WP;          // SGPR base
    const unsigned* xbu = (const unsigned*)xb;
    float* outb = out + (size_t)(b * 2) * HH * WW;        // SGPR base

    // 4 rows x 3 cols f16 neighborhood (8B cells)
    uint2 nbc[4][3];
#pragma unroll
    for (int dy = 0; dy < 4; ++dy)
#pragma unroll
        for (int dx = 0; dx < 3; ++dx)
            nbc[dy][dx] = xb[(h + dy) * WP + (w + dx)];

    // pixel-pair f32 vectors (cvt from f16), static indexing; live across loop
    f32x2 prs[3][3][4];
#pragma unroll
    for (int ky = 0; ky < 3; ++ky)
#pragma unroll
        for (int kx = 0; kx < 3; ++kx) {
            uint2 cA = nbc[ky][kx], cB = nbc[ky + 1][kx];
            prs[ky][kx][0] = (f32x2){hlo(cA.x), hlo(cB.x)};
            prs[ky][kx][1] = (f32x2){hhi(cA.x), hhi(cB.x)};
            prs[ky][kx][2] = (f32x2){hlo(cA.y), hlo(cB.y)};
            prs[ky][kx][3] = (f32x2){hhi(cA.y), hhi(cB.y)};
        }

    float acc0[2] = {0.f, 0.f};
    float acc1[2] = {0.f, 0.f};

#pragma unroll 3
    for (int n = 0; n < 9; ++n) {               // 3 iterations of 3 points
        int pny = n / 3 - 1;                    // uniform
        int pnx = n % 3 - 1;                    // uniform

        // ---- offsets for this point, both pixels (f32 pk_fma, exact) ----
        const float* wrA = w_p + n * 36;        // uniform SGPR address
        const float* wrB = w_p + (9 + n) * 36;
        f32x2 offy = {b_p[n], b_p[n]};          // uniform s_load
        f32x2 offx = {b_p[9 + n], b_p[9 + n]};
#pragma unroll
        for (int ky = 0; ky < 3; ++ky)
#pragma unroll
            for (int kx = 0; kx < 3; ++kx) {
                int t = ky * 3 + kx;
#pragma unroll
                for (int c = 0; c < 4; ++c) {
                    offy += wrA[c * 9 + t] * prs[ky][kx][c];
                    offx += wrB[c * 9 + t] * prs[ky][kx][c];
                }
            }

        // ---- packed coordinates / clamps / interp weights ----
        f32x2 py2 = (f32x2){(float)(h + 1 + pny), (float)(h + 2 + pny)} + offy;
        f32x2 px2 = (float)(w + 1 + pnx) + offx;
        f32x2 fy2 = {floorf(py2.x), floorf(py2.y)};
        f32x2 fx2 = {floorf(px2.x), floorf(px2.y)};
        f32x2 y0f = {fminf(fmaxf(fy2.x, 0.f), (float)(HP - 1)),
                     fminf(fmaxf(fy2.y, 0.f), (float)(HP - 1))};
        f32x2 y1f = {fminf(fmaxf(fy2.x + 1.f, 0.f), (float)(HP - 1)),
                     fminf(fmaxf(fy2.y + 1.f, 0.f), (float)(HP - 1))};
        f32x2 x0f = {fminf(fmaxf(fx2.x, 0.f), (float)(WP - 1)),
                     fminf(fmaxf(fx2.y, 0.f), (float)(WP - 1))};
        f32x2 x1f = {fminf(fmaxf(fx2.x + 1.f, 0.f), (float)(WP - 1)),
                     fminf(fmaxf(fx2.y + 1.f, 0.f), (float)(WP - 1))};
        f32x2 pyc = {fminf(fmaxf(py2.x, 0.f), (float)(HP - 1)),
                     fminf(fmaxf(py2.y, 0.f), (float)(HP - 1))};
        f32x2 pxc = {fminf(fmaxf(px2.x, 0.f), (float)(WP - 1)),
                     fminf(fmaxf(px2.y, 0.f), (float)(WP - 1))};
        f32x2 ay = 1.f + (y0f - pyc);
        f32x2 by = 1.f - (y1f - pyc);
        f32x2 ax = 1.f + (x0f - pxc);
        f32x2 bx = 1.f - (x1f - pxc);
        f32x2 glt = ay * ax, grb = by * bx, glb = ay * bx, grt = by * ax;

        // deform-conv weight packs (uniform s_load, runtime-n uniform addr)
        unsigned wd00 = pku(w_dc[0 * 36 + 0 * 9 + n], w_dc[0 * 36 + 1 * 9 + n]);
        unsigned wd01 = pku(w_dc[0 * 36 + 2 * 9 + n], w_dc[0 * 36 + 3 * 9 + n]);
        unsigned wd10 = pku(w_dc[1 * 36 + 0 * 9 + n], w_dc[1 * 36 + 1 * 9 + n]);
        unsigned wd11 = pku(w_dc[1 * 36 + 2 * 9 + n], w_dc[1 * 36 + 3 * 9 + n]);

#pragma unroll
        for (int p = 0; p < 2; ++p) {           // p compile-time
            int y0 = (int)(p ? y0f.y : y0f.x);
            int y1 = (int)(p ? y1f.y : y1f.x);
            int x0 = (int)(p ? x0f.y : x0f.x);
            int x1 = (int)(p ? x1f.y : x1f.x);
            float g_lt = p ? glt.y : glt.x;
            float g_rb = p ? grb.y : grb.x;
            float g_lb = p ? glb.y : glb.x;
            float g_rt = p ? grt.y : grt.x;

            // paired-row 16B loads: cells (y,x0) and (y,x0+1)
            uint4a q0 = *(const uint4a*)(xbu + 2 * (y0 * WP + x0));
            uint4a q1 = *(const uint4a*)(xbu + 2 * (y1 * WP + x0));
            bool ad = (x1 > x0);
            unsigned lt01 = q0.x, lt23 = q0.y;
            unsigned lb01 = ad ? q0.z : q0.x, lb23 = ad ? q0.w : q0.y;
            unsigned rt01 = q1.x, rt23 = q1.y;
            unsigned rb01 = ad ? q1.z : q1.x, rb23 = ad ? q1.w : q1.y;

            unsigned hlt = pku(g_lt, g_lt);
            unsigned hrb = pku(g_rb, g_rb);
            unsigned hlb = pku(g_lb, g_lb);
            unsigned hrt = pku(g_rt, g_rt);

            half2v h01 = b2h(hlt) * b2h(lt01) + b2h(hrb) * b2h(rb01)
                       + b2h(hlb) * b2h(lb01) + b2h(hrt) * b2h(rt01);
            half2v h23 = b2h(hlt) * b2h(lt23) + b2h(hrb) * b2h(rb23)
                       + b2h(hlb) * b2h(lb23) + b2h(hrt) * b2h(rt23);

            acc0[p] = dot2(h01, wd00, acc0[p]);
            acc0[p] = dot2(h23, wd01, acc0[p]);
            acc1[p] = dot2(h01, wd10, acc1[p]);
            acc1[p] = dot2(h23, wd11, acc1[p]);
        }
    }

#pragma unroll
    for (int p = 0; p < 2; ++p) {
        outb[(h + p) * WW + w] = acc0[p];
        outb[HH * WW + (h + p) * WW + w] = acc1[p];
    }
}

// ---------------------------------------------------------------------------
extern "C" void kernel_launch(void* const* d_in, const int* in_sizes, int n_in,
                              void* d_out, int out_size, void* d_ws, size_t ws_size,
                              hipStream_t stream) {
    const float* rgb  = (const float*)d_in[0];
    const float* sar  = (const float*)d_in[1];
    const float* w_fm = (const float*)d_in[2];
    const float* w_fs = (const float*)d_in[3];
    const float* w_p  = (const float*)d_in[4];
    const float* b_p  = (const float*)d_in[5];
    const float* w_dc = (const float*)d_in[6];
    float* out = (float*)d_out;

    // ws layout: fmp [512KB] | xph [BB*HP*WP uint2 + slack]
    float* ws = (float*)d_ws;
    float2* fmp = (float2*)ws;
    uint2* xph = (uint2*)(ws + 131072);                // 8B aligned

    k_fm<<<BB * 64, 128, 0, stream>>>(rgb, w_fm, fmp, xph);
    k_mat<<<BB * (HH / MROWS), 128, 0, stream>>>(rgb, sar, w_fs, fmp, xph);
    k_deform<<<BB * (HH / 2), 128, 0, stream>>>(w_p, b_p, w_dc, xph, out);
}

// Round 20
// 53.785 us; speedup vs baseline: 1.2584x; 1.2584x over previous
//
#include <hip/hip_runtime.h>
#include <math.h>

typedef __attribute__((ext_vector_type(2))) _Float16 half2v;
typedef __attribute__((ext_vector_type(2))) float f32x2;
typedef __attribute__((ext_vector_type(4), aligned(8))) unsigned int uint4a;

#define BB 4
#define HH 2048
#define WW 128
#define HP (HH + 2)   // 2050
#define WP (WW + 2)   // 130
#define PP 128        // pooled size
#define MROWS 8       // k_mat rows/block (R15/R18-proven best)

#define BORDER_PER_B (2 * WP + 2 * (HP - 2))   // 4356

__device__ __forceinline__ half2v b2h(unsigned u) { return __builtin_bit_cast(half2v, u); }
__device__ __forceinline__ unsigned pku(float a, float b) {
    return __builtin_bit_cast(unsigned, __builtin_amdgcn_cvt_pkrtz(a, b));
}
__device__ __forceinline__ float dot2(half2v a, unsigned wb, float c) {
    return __builtin_amdgcn_fdot2(a, b2h(wb), c, false);
}
__device__ __forceinline__ float hlo(unsigned u) { return (float)b2h(u).x; }
__device__ __forceinline__ float hhi(unsigned u) { return (float)b2h(u).y; }

// XCD co-location (R12-proven; R14 granularity win). XCD k = bid%8 owns
// batch k/2, rows [(k&1)*1024, +1024) in ALL producer/consumer kernels.

// ---------------------------------------------------------------------------
// Kernel 1: border-zero of xph (fused) + avg pool + 1x1 conv + sigmoid.
// (R15 frozen)
// ---------------------------------------------------------------------------
__global__ void k_fm(const float* __restrict__ rgb, const float* __restrict__ w_fm,
                     float2* __restrict__ fmp, uint2* __restrict__ xph) {
    int j = threadIdx.x;              // 0..127
    int bi = blockIdx.x;              // b*64 + t
    int tid = bi * 128 + j;

    if (tid < BB * BORDER_PER_B) {    // 17424 <= 32768 threads
        int b = tid / BORDER_PER_B;
        int r = tid - b * BORDER_PER_B;
        int row, col;
        if (r < WP)          { row = 0;      col = r; }
        else if (r < 2 * WP) { row = HP - 1; col = r - WP; }
        else {
            int q = r - 2 * WP;
            row = 1 + (q >> 1);
            col = (q & 1) ? (WP - 1) : 0;
        }
        xph[((size_t)b * HP + row) * WP + col] = make_uint2(0u, 0u);
    }

    int b = bi >> 6, t = bi & 63;     // fm rows 2t, 2t+1 <- rgb rows 32t..32t+31
    const float* r0 = rgb + ((size_t)(b * 2 + 0) * HH + (size_t)t * 32) * WW + j;
    const float* r1 = rgb + ((size_t)(b * 2 + 1) * HH + (size_t)t * 32) * WW + j;
    float sA0 = 0.f, sA1 = 0.f, sB0 = 0.f, sB1 = 0.f;
#pragma unroll
    for (int a = 0; a < 16; ++a) { sA0 += r0[a * WW]; sA1 += r1[a * WW]; }
#pragma unroll
    for (int a = 16; a < 32; ++a) { sB0 += r0[a * WW]; sB1 += r1[a * WW]; }
    sA0 *= (1.f / 16.f); sA1 *= (1.f / 16.f);
    sB0 *= (1.f / 16.f); sB1 *= (1.f / 16.f);
    float fA0 = w_fm[0] * sA0 + w_fm[1] * sA1;
    float fA1 = w_fm[2] * sA0 + w_fm[3] * sA1;
    float fB0 = w_fm[0] * sB0 + w_fm[1] * sB1;
    float fB1 = w_fm[2] * sB0 + w_fm[3] * sB1;
    float gA0 = 1.f / (1.f + expf(-fA0)), gB0 = 1.f / (1.f + expf(-fB0));
    float gA1 = 1.f / (1.f + expf(-fA1)), gB1 = 1.f / (1.f + expf(-fB1));
    fmp[((size_t)(b * 2 + 0) * 64 + t) * PP + j] = make_float2(gA0, gB0);
    fmp[((size_t)(b * 2 + 1) * 64 + t) * PP + j] = make_float2(gA1, gB1);
}

// ---------------------------------------------------------------------------
// Kernel 2: mat = rgb @ fm + rgb, fs = w_fs @ mat, xph = f16 cells.
// (R15 frozen: MROWS=8, k-pair float2 fm, v_pk_fma_f32 inner loop)
// ---------------------------------------------------------------------------
__global__ __launch_bounds__(128) void k_mat(
        const float* __restrict__ rgb, const float* __restrict__ sar,
        const float* __restrict__ w_fs, const float2* __restrict__ fmp,
        uint2* __restrict__ xph) {
    int w = threadIdx.x;              // 0..127
    int bid = blockIdx.x;             // 0..1023
    int swz = (bid & 7) * 128 + (bid >> 3);
    int b = swz >> 8;
    int h0 = (swz & 255) * 8;

    const float* rg0 = rgb + ((size_t)(b * 2 + 0) * HH + h0) * WW;  // uniform base
    const float* rg1 = rgb + ((size_t)(b * 2 + 1) * HH + h0) * WW;
    const float2* fp0 = fmp + (size_t)(b * 2 + 0) * 64 * PP;
    const float2* fp1 = fmp + (size_t)(b * 2 + 1) * 64 * PP;

    f32x2 av0[MROWS], av1[MROWS];
#pragma unroll
    for (int r = 0; r < MROWS; ++r) {                // residual term in lane .x
        av0[r] = (f32x2){rg0[r * WW + w], 0.f};
        av1[r] = (f32x2){rg1[r * WW + w], 0.f};
    }

#pragma unroll 4
    for (int t = 0; t < 64; ++t) {                   // k-pair (2t, 2t+1)
        float2 f0 = fp0[(size_t)t * PP + w];         // coalesced dwordx2
        float2 f1 = fp1[(size_t)t * PP + w];
        f32x2 fv0 = {f0.x, f0.y};
        f32x2 fv1 = {f1.x, f1.y};
#pragma unroll
        for (int r = 0; r < MROWS; ++r) {
            f32x2 a0 = *(const f32x2*)(rg0 + r * WW + 2 * t);   // uniform s_load
            f32x2 a1 = *(const f32x2*)(rg1 + r * WW + 2 * t);
            av0[r] += a0 * fv0;                      // v_pk_fma_f32
            av1[r] += a1 * fv1;
        }
    }

    float wa = w_fs[0], wb = w_fs[1], wc = w_fs[2], wd = w_fs[3];
#pragma unroll
    for (int r = 0; r < MROWS; ++r) {
        float m0 = av0[r].x + av0[r].y;
        float m1 = av1[r].x + av1[r].y;
        float fs0 = wa * m0 + wb * m1;
        float fs1 = wc * m0 + wd * m1;
        float s0 = sar[((size_t)(b * 2 + 0) * HH + (h0 + r)) * WW + w];
        float s1 = sar[((size_t)(b * 2 + 1) * HH + (h0 + r)) * WW + w];
        uint2 cell = make_uint2(pku(s0, s1), pku(fs0, fs1));
        xph[((size_t)b * HP + (h0 + r + 1)) * WP + (w + 1)] = cell;
    }
}

// ---------------------------------------------------------------------------
// Kernel 3: offset conv + deformable bilinear + deform conv, 2 px/thread,
// 128-thr blocks. ROLLED n-loop (unroll 1, R18-proven): per-point offsets
// computed in-iteration, static code ~6x smaller than fully-unrolled (I$
// resident). unroll 3 (R19) spilled (WRITE 20MB); unroll 1 is the optimum.
// ---------------------------------------------------------------------------
__global__ __launch_bounds__(128, 4) void k_deform(
        const float* __restrict__ w_p, const float* __restrict__ b_p,
        const float* __restrict__ w_dc, const uint2* __restrict__ xph,
        float* __restrict__ out) {
    int bid = blockIdx.x;
    int swz = (bid & 7) * 512 + (bid >> 3);
    int b = swz >> 10;
    int h = (swz & 1023) * 2;                   // this block: rows h, h+1 (uniform)
    int w = threadIdx.x;                        // 0..127

    const uint2* xb = xph + (size_t)b * HP * WP;          // SGPR base
    const unsigned* xbu = (const unsigned*)xb;
    float* outb = out + (size_t)(b * 2) * HH * WW;        // SGPR base

    // 4 rows x 3 cols f16 neighborhood (8B cells)
    uint2 nbc[4][3];
#pragma unroll
    for (int dy = 0; dy < 4; ++dy)
#pragma unroll
        for (int dx = 0; dx < 3; ++dx)
            nbc[dy][dx] = xb[(h + dy) * WP + (w + dx)];

    // pixel-pair f32 vectors (cvt from f16), static indexing; live across loop
    f32x2 prs[3][3][4];
#pragma unroll
    for (int ky = 0; ky < 3; ++ky)
#pragma unroll
        for (int kx = 0; kx < 3; ++kx) {
            uint2 cA = nbc[ky][kx], cB = nbc[ky + 1][kx];
            prs[ky][kx][0] = (f32x2){hlo(cA.x), hlo(cB.x)};
            prs[ky][kx][1] = (f32x2){hhi(cA.x), hhi(cB.x)};
            prs[ky][kx][2] = (f32x2){hlo(cA.y), hlo(cB.y)};
            prs[ky][kx][3] = (f32x2){hhi(cA.y), hhi(cB.y)};
        }

    float acc0[2] = {0.f, 0.f};
    float acc1[2] = {0.f, 0.f};

#pragma unroll 1
    for (int n = 0; n < 9; ++n) {               // ROLLED: 9 iterations
        int pny = n / 3 - 1;                    // uniform
        int pnx = n % 3 - 1;                    // uniform

        // ---- offsets for this point, both pixels (f32 pk_fma, exact) ----
        const float* wrA = w_p + n * 36;        // uniform SGPR address
        const float* wrB = w_p + (9 + n) * 36;
        f32x2 offy = {b_p[n], b_p[n]};          // uniform s_load
        f32x2 offx = {b_p[9 + n], b_p[9 + n]};
#pragma unroll
        for (int ky = 0; ky < 3; ++ky)
#pragma unroll
            for (int kx = 0; kx < 3; ++kx) {
                int t = ky * 3 + kx;
#pragma unroll
                for (int c = 0; c < 4; ++c) {
                    offy += wrA[c * 9 + t] * prs[ky][kx][c];
                    offx += wrB[c * 9 + t] * prs[ky][kx][c];
                }
            }

        // ---- packed coordinates / clamps / interp weights ----
        f32x2 py2 = (f32x2){(float)(h + 1 + pny), (float)(h + 2 + pny)} + offy;
        f32x2 px2 = (float)(w + 1 + pnx) + offx;
        f32x2 fy2 = {floorf(py2.x), floorf(py2.y)};
        f32x2 fx2 = {floorf(px2.x), floorf(px2.y)};
        f32x2 y0f = {fminf(fmaxf(fy2.x, 0.f), (float)(HP - 1)),
                     fminf(fmaxf(fy2.y, 0.f), (float)(HP - 1))};
        f32x2 y1f = {fminf(fmaxf(fy2.x + 1.f, 0.f), (float)(HP - 1)),
                     fminf(fmaxf(fy2.y + 1.f, 0.f), (float)(HP - 1))};
        f32x2 x0f = {fminf(fmaxf(fx2.x, 0.f), (float)(WP - 1)),
                     fminf(fmaxf(fx2.y, 0.f), (float)(WP - 1))};
        f32x2 x1f = {fminf(fmaxf(fx2.x + 1.f, 0.f), (float)(WP - 1)),
                     fminf(fmaxf(fx2.y + 1.f, 0.f), (float)(WP - 1))};
        f32x2 pyc = {fminf(fmaxf(py2.x, 0.f), (float)(HP - 1)),
                     fminf(fmaxf(py2.y, 0.f), (float)(HP - 1))};
        f32x2 pxc = {fminf(fmaxf(px2.x, 0.f), (float)(WP - 1)),
                     fminf(fmaxf(px2.y, 0.f), (float)(WP - 1))};
        f32x2 ay = 1.f + (y0f - pyc);
        f32x2 by = 1.f - (y1f - pyc);
        f32x2 ax = 1.f + (x0f - pxc);
        f32x2 bx = 1.f - (x1f - pxc);
        f32x2 glt = ay * ax, grb = by * bx, glb = ay * bx, grt = by * ax;

        // deform-conv weight packs (uniform s_load, runtime-n uniform addr)
        unsigned wd00 = pku(w_dc[0 * 36 + 0 * 9 + n], w_dc[0 * 36 + 1 * 9 + n]);
        unsigned wd01 = pku(w_dc[0 * 36 + 2 * 9 + n], w_dc[0 * 36 + 3 * 9 + n]);
        unsigned wd10 = pku(w_dc[1 * 36 + 0 * 9 + n], w_dc[1 * 36 + 1 * 9 + n]);
        unsigned wd11 = pku(w_dc[1 * 36 + 2 * 9 + n], w_dc[1 * 36 + 3 * 9 + n]);

#pragma unroll
        for (int p = 0; p < 2; ++p) {           // p compile-time
            int y0 = (int)(p ? y0f.y : y0f.x);
            int y1 = (int)(p ? y1f.y : y1f.x);
            int x0 = (int)(p ? x0f.y : x0f.x);
            int x1 = (int)(p ? x1f.y : x1f.x);
            float g_lt = p ? glt.y : glt.x;
            float g_rb = p ? grb.y : grb.x;
            float g_lb = p ? glb.y : glb.x;
            float g_rt = p ? grt.y : grt.x;

            // paired-row 16B loads: cells (y,x0) and (y,x0+1)
            uint4a q0 = *(const uint4a*)(xbu + 2 * (y0 * WP + x0));
            uint4a q1 = *(const uint4a*)(xbu + 2 * (y1 * WP + x0));
            bool ad = (x1 > x0);
            unsigned lt01 = q0.x, lt23 = q0.y;
            unsigned lb01 = ad ? q0.z : q0.x, lb23 = ad ? q0.w : q0.y;
            unsigned rt01 = q1.x, rt23 = q1.y;
            unsigned rb01 = ad ? q1.z : q1.x, rb23 = ad ? q1.w : q1.y;

            unsigned hlt = pku(g_lt, g_lt);
            unsigned hrb = pku(g_rb, g_rb);
            unsigned hlb = pku(g_lb, g_lb);
            unsigned hrt = pku(g_rt, g_rt);

            half2v h01 = b2h(hlt) * b2h(lt01) + b2h(hrb) * b2h(rb01)
                       + b2h(hlb) * b2h(lb01) + b2h(hrt) * b2h(rt01);
            half2v h23 = b2h(hlt) * b2h(lt23) + b2h(hrb) * b2h(rb23)
                       + b2h(hlb) * b2h(lb23) + b2h(hrt) * b2h(rt23);

            acc0[p] = dot2(h01, wd00, acc0[p]);
            acc0[p] = dot2(h23, wd01, acc0[p]);
            acc1[p] = dot2(h01, wd10, acc1[p]);
            acc1[p] = dot2(h23, wd11, acc1[p]);
        }
    }

#pragma unroll
    for (int p = 0; p < 2; ++p) {
        outb[(h + p) * WW + w] = acc0[p];
        outb[HH * WW + (h + p) * WW + w] = acc1[p];
    }
}

// ---------------------------------------------------------------------------
extern "C" void kernel_launch(void* const* d_in, const int* in_sizes, int n_in,
                              void* d_out, int out_size, void* d_ws, size_t ws_size,
                              hipStream_t stream) {
    const float* rgb  = (const float*)d_in[0];
    const float* sar  = (const float*)d_in[1];
    const float* w_fm = (const float*)d_in[2];
    const float* w_fs = (const float*)d_in[3];
    const float* w_p  = (const float*)d_in[4];
    const float* b_p  = (const float*)d_in[5];
    const float* w_dc = (const float*)d_in[6];
    float* out = (float*)d_out;

    // ws layout: fmp [512KB] | xph [BB*HP*WP uint2 + slack]
    float* ws = (float*)d_ws;
    float2* fmp = (float2*)ws;
    uint2* xph = (uint2*)(ws + 131072);                // 8B aligned

    k_fm<<<BB * 64, 128, 0, stream>>>(rgb, w_fm, fmp, xph);
    k_mat<<<BB * (HH / MROWS), 128, 0, stream>>>(rgb, sar, w_fs, fmp, xph);
    k_deform<<<BB * (HH / 2), 128, 0, stream>>>(w_p, b_p, w_dc, xph, out);
}